// Round 8
// baseline (1931.953 us; speedup 1.0000x reference)
//
#include <hip/hip_runtime.h>
#include <hip/hip_bf16.h>

#define HD 512      // d_model
#define NST 64      // d_state
#define NLAY 6
#define LSEQ 784
#define BB 64       // batch
#define QL 8        // lanes per channel
#define NS2 4       // float2-packed states per lane (8 complex states)
#define TL 112      // l-steps per LDS tile: 784 = 7*112, zero tail
#define CHB 64      // channels per block
#define NT 7        // tiles per sequence

typedef float v2f __attribute__((ext_vector_type(2)));

// Packed f32 math via inline asm (VOP3P).
__device__ __forceinline__ v2f pk_fma(v2f a, v2f b, v2f c)
{
    v2f d;
    asm("v_pk_fma_f32 %0, %1, %2, %3" : "=v"(d) : "v"(a), "v"(b), "v"(c));
    return d;
}
// d = (-a)*b + c
__device__ __forceinline__ v2f pk_fma_na(v2f a, v2f b, v2f c)
{
    v2f d;
    asm("v_pk_fma_f32 %0, %1, %2, %3 neg_lo:[1,0,0] neg_hi:[1,0,0]"
        : "=v"(d) : "v"(a), "v"(b), "v"(c));
    return d;
}
__device__ __forceinline__ v2f pk_mul(v2f a, v2f b)
{
    v2f d;
    asm("v_pk_mul_f32 %0, %1, %2" : "=v"(d) : "v"(a), "v"(b));
    return d;
}

// DPP adds: xor1 + xor2 (quad_perm) + row_half_mirror -> all 8 lanes of a
// group hold the 8-lane total. Pure VALU.
template <int CTRL>
__device__ __forceinline__ float dpp_add(float x)
{
    int xi = __builtin_bit_cast(int, x);
    int yi = __builtin_amdgcn_update_dpp(0, xi, CTRL, 0xF, 0xF, true);
    return x + __builtin_bit_cast(float, yi);
}

// ---------------------------------------------------------------------------
// Precompute lambda = exp(dt*A) and 2*Cd per (layer,n,h), [layer][n][h].
// ---------------------------------------------------------------------------
__global__ void precompute_k(const float* __restrict__ log_dt,
                             const float* __restrict__ log_A_real,
                             const float* __restrict__ A_imag,
                             const float* __restrict__ C_re,
                             const float* __restrict__ C_im,
                             float* __restrict__ lamr, float* __restrict__ lami,
                             float* __restrict__ cdr,  float* __restrict__ cdi)
{
    int t = blockIdx.x * blockDim.x + threadIdx.x;
    if (t >= NLAY * HD * NST) return;
    int n  = t % NST;
    int ih = t / NST;          // i*HD + h
    int i  = ih / HD;
    int h  = ih % HD;

    float dt  = expf(log_dt[ih]);
    float are = -expf(log_A_real[t]);
    float aim = A_imag[t];
    float dr = are * dt, di = aim * dt;
    float er = expf(dr);
    float sn, cs;
    __sincosf(di, &sn, &cs);
    float lr = er * cs, li = er * sn;  // lambda = exp(dt*A)
    float e1r = lr - 1.0f, e1i = li;
    float den = are * are + aim * aim;
    float qr = (e1r * are + e1i * aim) / den;
    float qi = (e1i * are - e1r * aim) / den;
    float crv = C_re[t], civ = C_im[t];
    float cdre = crv * qr - civ * qi;
    float cdim = crv * qi + civ * qr;

    size_t o = ((size_t)i * NST + n) * HD + h;
    lamr[o] = lr; lami[o] = li;
    cdr[o] = 2.0f * cdre; cdi[o] = 2.0f * cdim;
}

// ---------------------------------------------------------------------------
// Encoder: u[b,l,h] = x[b,l] * enc_w[h] + enc_b[h]
// ---------------------------------------------------------------------------
__global__ void encoder_k(const float* __restrict__ x, const float* __restrict__ ew,
                          const float* __restrict__ eb, float* __restrict__ u)
{
    size_t g = (size_t)blockIdx.x * blockDim.x + threadIdx.x;
    if (g >= (size_t)BB * LSEQ * HD) return;
    int h = (int)(g % HD);
    size_t bl = g / HD;
    u[g] = fmaf(x[bl], ew[h], eb[h]);
}

// ---------------------------------------------------------------------------
// Fused SSM scan + residual, IN PLACE on u, double-buffered LDS tiles,
// ONE barrier per tile.
// Block = 512 thr = 64 channels (one b) x QL=8 lanes. Lane q of each
// 8-group holds complex states q*8..q*8+7 (NS2=4 float2, v_pk_* ops).
// Per tile t (after the single barrier ending tile t-1):
//   (a) ds_read y of tile t-1 from `stg` + global store (fire-and-forget)
//   (b) overwrite `stg` with prefetched tile t+1 input  [safe: (a) and (b)
//       touch per-thread-identical address sets; same-wave DS ops are
//       in-order, so each thread's read precedes its own overwrite]
//   (c) issue global loads for tile t+2 (consumed one full tile later)
//   (d) compute on `comp` (staged at t-1), y written in place
// Channels are partitioned per-wave (cl = thr>>3), so compute-phase LDS
// reads/writes of (l, cl) slots never cross waves. Buffers swap each tile.
// ---------------------------------------------------------------------------
__global__ __launch_bounds__(512, 4)
void scan_k(float* __restrict__ u,
            const float* __restrict__ lamr, const float* __restrict__ lami,
            const float* __restrict__ cdr,  const float* __restrict__ cdi,
            const float* __restrict__ Dvec)
{
    __shared__ float buf[2][TL * CHB];   // 2 x 28 KB

    const int thr = threadIdx.x;
    const int ch0 = blockIdx.x * CHB;     // flat channel base (b*HD + h0)
    const int b   = ch0 >> 9;             // HD = 512
    const int h0  = ch0 & (HD - 1);
    const int cl  = thr >> 3;             // channel within block (0..63)
    const int q   = thr & 7;              // state octant
    const int h   = h0 + cl;
    const int n0  = q * (2 * NS2);
    const float dcoef = 1.0f + Dvec[h];

    v2f lr[NS2], lim[NS2], cr[NS2], nci[NS2], sr[NS2], si[NS2];
#pragma unroll
    for (int j = 0; j < NS2; j++) {
        size_t o = (size_t)(n0 + 2 * j) * HD + h;   // states 2j, 2j+1
        lr[j]  = v2f{lamr[o], lamr[o + HD]};
        lim[j] = v2f{lami[o], lami[o + HD]};
        cr[j]  = v2f{cdr[o], cdr[o + HD]};
        nci[j] = v2f{-cdi[o], -cdi[o + HD]};
        sr[j]  = v2f{0.f, 0.f};
        si[j]  = v2f{0.f, 0.f};
    }

    // staging partition: 112 rows x 16 float4 = 1792 slots; thread owns
    // f = thr + p*512 (p=0..3; p==3 only for thr<256)
    const size_t ubase = (size_t)b * LSEQ * HD + h0;
    int rows[4], cols[4];
    bool act[4];
#pragma unroll
    for (int p = 0; p < 4; p++) {
        int f = thr + p * 512;
        act[p]  = f < TL * 16;
        rows[p] = f >> 4;
        cols[p] = (f & 15) * 4;
    }

    float* comp = buf[0];
    float* stg  = buf[1];
    float4 pre[4];

    // prologue: tile 0 -> comp; issue tile 1 loads
#pragma unroll
    for (int p = 0; p < 4; p++)
        if (act[p]) pre[p] = *(const float4*)&u[ubase + (size_t)rows[p] * HD + cols[p]];
#pragma unroll
    for (int p = 0; p < 4; p++)
        if (act[p]) *(float4*)&comp[rows[p] * CHB + cols[p]] = pre[p];
#pragma unroll
    for (int p = 0; p < 4; p++)
        if (act[p]) pre[p] = *(const float4*)&u[ubase + (size_t)(TL + rows[p]) * HD + cols[p]];
    __syncthreads();

    for (int t = 0; t < NT; t++) {
        if (t > 0) {   // (a) store y of tile t-1 from stg
            size_t l0p = (size_t)(t - 1) * TL;
            float4 yv[4];
#pragma unroll
            for (int p = 0; p < 4; p++)
                if (act[p]) yv[p] = *(const float4*)&stg[rows[p] * CHB + cols[p]];
#pragma unroll
            for (int p = 0; p < 4; p++)
                if (act[p]) *(float4*)&u[ubase + (l0p + rows[p]) * HD + cols[p]] = yv[p];
        }
        if (t + 1 < NT) {   // (b) restage stg with tile t+1 input
#pragma unroll
            for (int p = 0; p < 4; p++)
                if (act[p]) *(float4*)&stg[rows[p] * CHB + cols[p]] = pre[p];
            if (t + 2 < NT) {   // (c) issue tile t+2 loads
                size_t l0n = (size_t)(t + 2) * TL;
#pragma unroll
                for (int p = 0; p < 4; p++)
                    if (act[p]) pre[p] = *(const float4*)&u[ubase + (l0n + rows[p]) * HD + cols[p]];
            }
        }

        // (d) compute on comp, y in place
        for (int lo = 0; lo < TL; lo += 8) {
#pragma unroll
            for (int lu = 0; lu < 8; lu++) {
                int l = lo + lu;
                float uv = comp[l * CHB + cl];
                v2f uv2 = v2f{uv, uv};
                v2f ya = v2f{0.f, 0.f}, yb = v2f{0.f, 0.f};
#pragma unroll
                for (int j = 0; j < NS2; j++) {
                    v2f t0  = pk_fma_na(lim[j], si[j], uv2);  // -li*si + uv
                    v2f nsr = pk_fma(lr[j], sr[j], t0);
                    v2f tmp = pk_mul(lim[j], sr[j]);
                    v2f nsi = pk_fma(lr[j], si[j], tmp);
                    sr[j] = nsr; si[j] = nsi;
                    ya = pk_fma(cr[j], nsr, ya);
                    yb = pk_fma(nci[j], nsi, yb);
                }
                v2f ys = ya + yb;
                float y = ys.x + ys.y;
                y = dpp_add<0xB1>(y);     // quad_perm xor 1
                y = dpp_add<0x4E>(y);     // quad_perm xor 2
                y = dpp_add<0x141>(y);    // row_half_mirror (8-lane total)
                if (q == 0) comp[l * CHB + cl] = fmaf(uv, dcoef, y);
            }
        }

        __syncthreads();                  // the ONE barrier per tile
        float* tswap = comp; comp = stg; stg = tswap;
    }

    // epilogue: y of last tile now in stg
    {
        size_t l0p = (size_t)(NT - 1) * TL;
        float4 yv[4];
#pragma unroll
        for (int p = 0; p < 4; p++)
            if (act[p]) yv[p] = *(const float4*)&stg[rows[p] * CHB + cols[p]];
#pragma unroll
        for (int p = 0; p < 4; p++)
            if (act[p]) *(float4*)&u[ubase + (l0p + rows[p]) * HD + cols[p]] = yv[p];
    }
}

// ---------------------------------------------------------------------------
// In-place LayerNorm over H. One wave per (b,l) row; 8 floats per lane.
// ---------------------------------------------------------------------------
__global__ void ln_k(float* __restrict__ u, const float* __restrict__ gp,
                     const float* __restrict__ bp)
{
    int wid  = threadIdx.x >> 6;
    int lane = threadIdx.x & 63;
    size_t row = (size_t)blockIdx.x * 4 + wid;   // < BB*LSEQ exactly
    float* up = u + row * HD;

    float4 a0 = ((const float4*)up)[lane];
    float4 a1 = ((const float4*)up)[64 + lane];
    float v[8] = {a0.x, a0.y, a0.z, a0.w, a1.x, a1.y, a1.z, a1.w};
    int h0 = lane * 4, h1 = 256 + lane * 4;

    float s = 0.f;
#pragma unroll
    for (int j = 0; j < 8; j++) s += v[j];
#pragma unroll
    for (int m = 32; m >= 1; m >>= 1) s += __shfl_xor(s, m, 64);
    float mu = s * (1.0f / HD);

    float qq = 0.f;
#pragma unroll
    for (int j = 0; j < 8; j++) { float d = v[j] - mu; qq += d * d; }
#pragma unroll
    for (int m = 32; m >= 1; m >>= 1) qq += __shfl_xor(qq, m, 64);
    float rs = rsqrtf(qq * (1.0f / HD) + 1e-5f);

    float o[8];
#pragma unroll
    for (int j = 0; j < 8; j++) {
        int h = (j < 4) ? (h0 + j) : (h1 + j - 4);
        o[j] = fmaf((v[j] - mu) * rs, gp[h], bp[h]);
    }
    ((float4*)up)[lane]      = {o[0], o[1], o[2], o[3]};
    ((float4*)up)[64 + lane] = {o[4], o[5], o[6], o[7]};
}

// ---------------------------------------------------------------------------
// Mean-pool over L: pooled[b,h] = mean_l u[b,l,h]
// ---------------------------------------------------------------------------
__global__ void pool_k(const float* __restrict__ u, float* __restrict__ p)
{
    int g = blockIdx.x * blockDim.x + threadIdx.x;
    if (g >= BB * HD) return;
    int h = g & (HD - 1);
    int b = g >> 9;
    const float* up = u + (size_t)b * LSEQ * HD + h;
    float s = 0.f;
    for (int l = 0; l < LSEQ; l++) s += up[(size_t)l * HD];
    p[g] = s * (1.0f / LSEQ);
}

// ---------------------------------------------------------------------------
// Decoder: out[b,c] = pooled[b,:] @ dec_w[:,c] + dec_b[c]
// ---------------------------------------------------------------------------
__global__ void dec_k(const float* __restrict__ p, const float* __restrict__ w,
                      const float* __restrict__ bias, float* __restrict__ out)
{
    int t = blockIdx.x * blockDim.x + threadIdx.x;
    if (t >= BB * 10) return;
    int c = t % 10, b = t / 10;
    float acc = bias[c];
    const float* pb = p + b * HD;
    for (int h = 0; h < HD; h++) acc = fmaf(pb[h], w[h * 10 + c], acc);
    out[t] = acc;
}

// ---------------------------------------------------------------------------
extern "C" void kernel_launch(void* const* d_in, const int* in_sizes, int n_in,
                              void* d_out, int out_size, void* d_ws, size_t ws_size,
                              hipStream_t stream)
{
    const float* x   = (const float*)d_in[0];
    const float* ew  = (const float*)d_in[1];
    const float* eb  = (const float*)d_in[2];
    const float* ldt = (const float*)d_in[3];
    const float* lar = (const float*)d_in[4];
    const float* aim = (const float*)d_in[5];
    const float* cre = (const float*)d_in[6];
    const float* cim = (const float*)d_in[7];
    const float* Dp  = (const float*)d_in[8];
    const float* lng = (const float*)d_in[9];
    const float* lnb = (const float*)d_in[10];
    const float* fng = (const float*)d_in[11];
    const float* fnb = (const float*)d_in[12];
    const float* dw  = (const float*)d_in[13];
    const float* db  = (const float*)d_in[14];
    float* out = (float*)d_out;

    float* ws = (float*)d_ws;
    const size_t SZ = (size_t)BB * LSEQ * HD;   // 25,690,112 floats (103 MB)
    const size_t P  = (size_t)NLAY * NST * HD;  // 196,608 floats
    float* U  = ws;                              // residual stream, in-place
    float* LR = ws + SZ + 4 * HD;
    float* LI = LR + P;
    float* CR = LI + P;
    float* CI = CR + P;
    float* PO = CI + P;                          // BB*HD floats
    // total: ~106 MB

    precompute_k<<<(NLAY * HD * NST + 255) / 256, 256, 0, stream>>>(
        ldt, lar, aim, cre, cim, LR, LI, CR, CI);
    encoder_k<<<(int)((SZ + 255) / 256), 256, 0, stream>>>(x, ew, eb, U);

    for (int i = 0; i < NLAY; i++) {
        size_t po = (size_t)i * NST * HD;
        scan_k<<<BB * HD / CHB, 512, 0, stream>>>(
            U, LR + po, LI + po, CR + po, CI + po, Dp + i * HD);
        ln_k<<<BB * LSEQ / 4, 256, 0, stream>>>(U, lng + i * HD, lnb + i * HD);
    }
    ln_k<<<BB * LSEQ / 4, 256, 0, stream>>>(U, fng, fnb);
    pool_k<<<BB * HD / 256, 256, 0, stream>>>(U, PO);
    dec_k<<<(BB * 10 + 255) / 256, 256, 0, stream>>>(PO, dw, db, out);
}

// Round 9
// 991.094 us; speedup vs baseline: 1.9493x; 1.9493x over previous
//
#include <hip/hip_runtime.h>
#include <hip/hip_bf16.h>

#define HD 512      // d_model
#define NST 64      // d_state
#define NLAY 6
#define LSEQ 784
#define BB 64       // batch
#define CHK 7       // l-tiles (16 rows) per conv block; 49 = 7*7
#define NKA 848     // reversed+padded kernel array length (u16)
#define TOFF 798    // KA[t] = K[TOFF - t]; t in [15,798] real, else 0

typedef short s8v __attribute__((ext_vector_type(8)));   // 8 bf16 (4 VGPR)
typedef float f4v __attribute__((ext_vector_type(4)));   // MFMA acc

// fp32 -> bf16 bits, round-to-nearest-even
__device__ __forceinline__ unsigned f2b(float f)
{
    unsigned u = __builtin_bit_cast(unsigned, f);
    return (u + 0x7FFFu + ((u >> 16) & 1u)) >> 16;
}

// ---------------------------------------------------------------------------
// Per (layer,h,n): lambda = exp(dt*A), dtA (for direct powers), 2*Cd.
// Layout [i][h][n] (n-inner).
// ---------------------------------------------------------------------------
__global__ void precompute_k(const float* __restrict__ log_dt,
                             const float* __restrict__ log_A_real,
                             const float* __restrict__ A_imag,
                             const float* __restrict__ C_re,
                             const float* __restrict__ C_im,
                             float* __restrict__ lamr, float* __restrict__ lami,
                             float* __restrict__ dtr,  float* __restrict__ dti,
                             float* __restrict__ c2r,  float* __restrict__ c2i)
{
    int t = blockIdx.x * 256 + threadIdx.x;
    if (t >= NLAY * HD * NST) return;
    int ih = t >> 6;                       // i*HD + h
    float dt  = expf(log_dt[ih]);
    float are = -expf(log_A_real[t]);
    float aim = A_imag[t];
    float dr = are * dt, di = aim * dt;
    float er = expf(dr);
    float sn, cs; __sincosf(di, &sn, &cs);
    float lr = er * cs, li = er * sn;      // lambda
    float e1r = lr - 1.0f, e1i = li;
    float den = are * are + aim * aim;
    float qr = (e1r * are + e1i * aim) / den;
    float qi = (e1i * are - e1r * aim) / den;
    float crv = C_re[t], civ = C_im[t];
    lamr[t] = lr; lami[t] = li; dtr[t] = dr; dti[t] = di;
    c2r[t] = 2.0f * (crv * qr - civ * qi);
    c2i[t] = 2.0f * (crv * qi + civ * qr);
}

// ---------------------------------------------------------------------------
// Build KA[i][h][t] (bf16): reversed, zero-padded conv kernel.
// K[d] = sum_n 2Re(Cd_n lam_n^d), d = 0..783; KA[TOFF-d] = K[d], pads = 0.
// Thread = (i,h,dc): 16 consecutive d's; lam^d0 anchored by exp/sincos,
// then iterated (amortizes transcendentals 1/16).
// ---------------------------------------------------------------------------
__global__ void kq_k(const float* __restrict__ lamr, const float* __restrict__ lami,
                     const float* __restrict__ dtr,  const float* __restrict__ dti,
                     const float* __restrict__ c2r,  const float* __restrict__ c2i,
                     unsigned short* __restrict__ KA)
{
    int t = blockIdx.x * 256 + threadIdx.x;   // < 6*512*49
    int dc = t % 49;
    int ih = t / 49;                          // i*HD + h
    int d0 = dc * 16;
    float acc[16];
#pragma unroll
    for (int k = 0; k < 16; k++) acc[k] = 0.f;
    int base = ih * 64;
    for (int n = 0; n < 64; n++) {
        float lr = lamr[base + n], li = lami[base + n];
        float dr = dtr[base + n],  di = dti[base + n];
        float cr = c2r[base + n],  ci = c2i[base + n];
        float e = __expf(dr * (float)d0);
        float sn, cs; __sincosf(di * (float)d0, &sn, &cs);
        float pr = e * cs, pi = e * sn;       // lam^d0
#pragma unroll
        for (int k = 0; k < 16; k++) {
            acc[k] = fmaf(cr, pr, fmaf(-ci, pi, acc[k]));
            float nr = pr * lr - pi * li;
            pi = fmaf(pr, li, pi * lr);
            pr = nr;
        }
    }
    unsigned short* kap = KA + (size_t)ih * NKA;
#pragma unroll
    for (int k = 0; k < 16; k++)
        kap[TOFF - (d0 + k)] = (unsigned short)f2b(acc[k]);
    if (dc == 0)  for (int z = TOFF + 1; z < NKA; z++) kap[z] = 0;
    if (dc == 48) for (int z = 0; z < TOFF - 783; z++) kap[z] = 0;
}

// ---------------------------------------------------------------------------
// Encoder into [l][h][b] layout: V[(l*HD+h)*BB+b] = x[b,l]*ew[h]+eb[h]
// ---------------------------------------------------------------------------
__global__ void encoder_k(const float* __restrict__ x, const float* __restrict__ ew,
                          const float* __restrict__ eb, float* __restrict__ V)
{
    size_t g = (size_t)blockIdx.x * 256 + threadIdx.x;
    int b = (int)(g & 63);
    int h = (int)((g >> 6) & 511);
    int l = (int)(g >> 15);
    V[g] = fmaf(x[b * LSEQ + l], ew[h], eb[h]);
}

// ---------------------------------------------------------------------------
// MFMA causal-Toeplitz conv + residual: V2 = conv(K_h, V) + (1+D_h)*V.
// Block = (h, chunk c of 7 l-tiles) x 4 waves (4 b-tiles of 16).
// A[m][k] = K_h[(l0+m)-(j0+k)] from LDS KA copy (zeros => causality).
// B[k][n] = u[j0+k][b0+n] bf16, staged in double-buffered LDS (dword pairs
// over j so B-frag = 4x ds_read_b32, stage = 4x ds_write_b32, ~2-way banks).
// A-frag: parity-duplicated KS (KSodd[t]=KS[t+1]) => 4x aligned ds_read_b32.
// One barrier per j-step; next tile's global loads issued before compute.
// ---------------------------------------------------------------------------
__global__ __launch_bounds__(256)
void conv_k(const float* __restrict__ V, float* __restrict__ V2,
            const unsigned short* __restrict__ KA, const float* __restrict__ Dvec)
{
    __shared__ unsigned short KS[2 * NKA];   // [0..847] rev-K, [848..1695] odd-shift
    __shared__ unsigned UT[2][64 * 17];      // [buf][b*17 + jj], jj = j/2

    const int thr = threadIdx.x;
    const int h   = blockIdx.x & 511;
    const int c   = blockIdx.x >> 9;         // 0..6
    const int wid = thr >> 6;                // b-tile
    const int lane = thr & 63;
    const int n = lane & 15;
    const int q = lane >> 4;
    const int JTN = (112 * c + 111) / 32 + 1;

    // stage KS + odd-shifted copy
    const unsigned short* kap = KA + (size_t)h * NKA;
    for (int idx = thr; idx < NKA; idx += 256) {
        unsigned short v = kap[idx];
        KS[idx] = v;
        if (idx) KS[NKA + idx - 1] = v;
    }
    if (thr == 0) KS[2 * NKA - 1] = 0;

    // stage tile jt=0
    const int jj = thr >> 4;                 // 0..15 (j pair)
    const int bq = thr & 15;                 // 0..15 (b quad)
    {
        const float* p = &V[((size_t)(2 * jj) * HD + h) * BB + 4 * bq];
        float4 r0 = *(const float4*)p;
        float4 r1 = *(const float4*)(p + (size_t)HD * BB);
        unsigned* up = &UT[0][0];
        up[(4 * bq + 0) * 17 + jj] = f2b(r0.x) | (f2b(r1.x) << 16);
        up[(4 * bq + 1) * 17 + jj] = f2b(r0.y) | (f2b(r1.y) << 16);
        up[(4 * bq + 2) * 17 + jj] = f2b(r0.z) | (f2b(r1.z) << 16);
        up[(4 * bq + 3) * 17 + jj] = f2b(r0.w) | (f2b(r1.w) << 16);
    }
    __syncthreads();

    f4v acc[CHK];
#pragma unroll
    for (int i = 0; i < CHK; i++) acc[i] = (f4v){0.f, 0.f, 0.f, 0.f};

    const float dcoef = 1.0f + Dvec[h];

    for (int jt = 0; jt < JTN; ++jt) {
        const int buf = jt & 1;
        const int j0 = jt * 32;
        // issue next tile's global loads (consumed after compute)
        float4 r0, r1;
        const bool more = (jt + 1) < JTN;
        if (more) {
            int j = (jt + 1) * 32 + 2 * jj;  // rows >783 read junk, killed by zero-A
            const float* p = &V[((size_t)j * HD + h) * BB + 4 * bq];
            r0 = *(const float4*)p;
            r1 = *(const float4*)(p + (size_t)HD * BB);
        }
        // B fragment (same for all l-tiles this step)
        union { unsigned u[4]; s8v v; } bu;
        {
            const unsigned* bp = &UT[buf][(wid * 16 + n) * 17 + q * 4];
            bu.u[0] = bp[0]; bu.u[1] = bp[1]; bu.u[2] = bp[2]; bu.u[3] = bp[3];
        }
#pragma unroll
        for (int lt = 0; lt < CHK; ++lt) {
            const int Lt = c * CHK + lt;
            if (16 * Lt + 15 < j0) continue;            // inactive (uniform)
            const int l0 = Lt * 16;
            int tb = (TOFF - l0 + j0) + 8 * q - n;      // lane's first KA index
            int par = tb & 1;
            int byteoff = 2 * tb + (par ? (2 * NKA - 2) : 0);
            const unsigned* ap = (const unsigned*)((const char*)KS + byteoff);
            union { unsigned u[4]; s8v v; } au;
            au.u[0] = ap[0]; au.u[1] = ap[1]; au.u[2] = ap[2]; au.u[3] = ap[3];
            acc[lt] = __builtin_amdgcn_mfma_f32_16x16x32_bf16(au.v, bu.v, acc[lt], 0, 0, 0);
        }
        if (more) {
            unsigned* up = &UT[buf ^ 1][0];
            up[(4 * bq + 0) * 17 + jj] = f2b(r0.x) | (f2b(r1.x) << 16);
            up[(4 * bq + 1) * 17 + jj] = f2b(r0.y) | (f2b(r1.y) << 16);
            up[(4 * bq + 2) * 17 + jj] = f2b(r0.z) | (f2b(r1.z) << 16);
            up[(4 * bq + 3) * 17 + jj] = f2b(r0.w) | (f2b(r1.w) << 16);
        }
        __syncthreads();
    }

    // epilogue: V2 = y + (1+D)*u  (pre-LN residual), fp32
#pragma unroll
    for (int lt = 0; lt < CHK; ++lt) {
        const int l0 = (c * CHK + lt) * 16;
#pragma unroll
        for (int r = 0; r < 4; ++r) {
            int l = l0 + q * 4 + r;
            size_t a = ((size_t)l * HD + h) * BB + wid * 16 + n;
            V2[a] = fmaf(dcoef, V[a], acc[lt][r]);
        }
    }
}

// ---------------------------------------------------------------------------
// LayerNorm over h in [l][h][b] layout. Block = one l, 512 threads:
// thread (b = thr&63, hg = thr>>6) holds 64 h-values in registers.
// ---------------------------------------------------------------------------
__global__ __launch_bounds__(512)
void lnT_k(const float* __restrict__ src, float* __restrict__ dst,
           const float* __restrict__ gp, const float* __restrict__ bp)
{
    __shared__ float red[8][64], redq[8][64], mus[64], rss[64];
    __shared__ float gs[512], bs[512];
    const int thr = threadIdx.x;
    const int b = thr & 63;
    const int hg = thr >> 6;
    const size_t l = blockIdx.x;
    gs[thr] = gp[thr]; bs[thr] = bp[thr];

    const float* sp = &src[(l * HD + hg * 64) * BB + b];
    float v[64];
    float s = 0.f, sq = 0.f;
#pragma unroll
    for (int k = 0; k < 64; k++) {
        float x = sp[(size_t)k * BB];
        v[k] = x; s += x; sq = fmaf(x, x, sq);
    }
    red[hg][b] = s; redq[hg][b] = sq;
    __syncthreads();
    if (thr < 64) {
        float ts = 0.f, tq = 0.f;
#pragma unroll
        for (int k = 0; k < 8; k++) { ts += red[k][thr]; tq += redq[k][thr]; }
        float mu = ts * (1.0f / HD);
        mus[thr] = mu;
        rss[thr] = rsqrtf(tq * (1.0f / HD) - mu * mu + 1e-5f);
    }
    __syncthreads();
    float mu = mus[b], rs = rss[b];
    float* dp = &dst[(l * HD + hg * 64) * BB + b];
#pragma unroll
    for (int k = 0; k < 64; k++) {
        int hh = hg * 64 + k;
        dp[(size_t)k * BB] = fmaf((v[k] - mu) * rs, gs[hh], bs[hh]);
    }
}

// ---------------------------------------------------------------------------
// Mean-pool over l: PO[h*64+b] = mean_l V2[l][h][b]. Block per h.
// ---------------------------------------------------------------------------
__global__ void pool_k(const float* __restrict__ V2, float* __restrict__ PO)
{
    __shared__ float red[4][64];
    int h = blockIdx.x;
    int b = threadIdx.x & 63;
    int lg = threadIdx.x >> 6;               // 0..3
    const float* p = &V2[(size_t)h * BB + b];
    float s = 0.f;
    for (int l = lg; l < LSEQ; l += 4) s += p[(size_t)l * HD * BB];
    red[lg][b] = s;
    __syncthreads();
    if (threadIdx.x < 64) {
        float t = red[0][b] + red[1][b] + red[2][b] + red[3][b];
        PO[h * BB + b] = t * (1.0f / LSEQ);
    }
}

// ---------------------------------------------------------------------------
// Decoder: out[b,c] = PO[:,b] . dec_w[:,c] + dec_b[c]
// ---------------------------------------------------------------------------
__global__ void dec_k(const float* __restrict__ PO, const float* __restrict__ w,
                      const float* __restrict__ bias, float* __restrict__ out)
{
    int t = blockIdx.x * 256 + threadIdx.x;
    if (t >= BB * 10) return;
    int cc = t % 10, b = t / 10;
    float acc = bias[cc];
    for (int hh = 0; hh < HD; hh++)
        acc = fmaf(PO[hh * BB + b], w[hh * 10 + cc], acc);
    out[t] = acc;
}

// ---------------------------------------------------------------------------
extern "C" void kernel_launch(void* const* d_in, const int* in_sizes, int n_in,
                              void* d_out, int out_size, void* d_ws, size_t ws_size,
                              hipStream_t stream)
{
    const float* x   = (const float*)d_in[0];
    const float* ew  = (const float*)d_in[1];
    const float* eb  = (const float*)d_in[2];
    const float* ldt = (const float*)d_in[3];
    const float* lar = (const float*)d_in[4];
    const float* aim = (const float*)d_in[5];
    const float* cre = (const float*)d_in[6];
    const float* cim = (const float*)d_in[7];
    const float* Dp  = (const float*)d_in[8];
    const float* lng = (const float*)d_in[9];
    const float* lnb = (const float*)d_in[10];
    const float* fng = (const float*)d_in[11];
    const float* fnb = (const float*)d_in[12];
    const float* dw  = (const float*)d_in[13];
    const float* db  = (const float*)d_in[14];
    float* out = (float*)d_out;

    float* ws = (float*)d_ws;
    const size_t SZ = (size_t)BB * LSEQ * HD;    // 25,690,112 floats
    const size_t PP = (size_t)NLAY * HD * NST;   // 196,608
    float* V   = ws;                  // residual stream, [l][h][b]
    float* V2  = ws + SZ;             // conv/pre-LN buffer (also absorbs the
                                      // harmless j>783 over-reads from conv)
    float* PAR = ws + 2 * SZ;
    float* lamr = PAR,        * lami = PAR + PP;
    float* dtr  = PAR + 2*PP, * dti  = PAR + 3*PP;
    float* c2r  = PAR + 4*PP, * c2i  = PAR + 5*PP;
    unsigned short* KA = (unsigned short*)(PAR + 6 * PP);  // 6*512*848 u16
    float* PO = PAR + 6 * PP + (NLAY * HD * NKA) / 2;      // 32768 floats
    // total ~215.6 MB

    precompute_k<<<(NLAY * HD * NST + 255) / 256, 256, 0, stream>>>(
        ldt, lar, aim, cre, cim, lamr, lami, dtr, dti, c2r, c2i);
    kq_k<<<(NLAY * HD * 49) / 256, 256, 0, stream>>>(
        lamr, lami, dtr, dti, c2r, c2i, KA);
    encoder_k<<<(int)(SZ / 256), 256, 0, stream>>>(x, ew, eb, V);

    for (int i = 0; i < NLAY; i++) {
        conv_k<<<512 * CHK, 256, 0, stream>>>(
            V, V2, KA + (size_t)i * HD * NKA, Dp + i * HD);
        lnT_k<<<LSEQ, 512, 0, stream>>>(V2, V, lng + i * HD, lnb + i * HD);
    }
    lnT_k<<<LSEQ, 512, 0, stream>>>(V, V2, fng, fnb);
    pool_k<<<HD, 256, 0, stream>>>(V2, PO);
    dec_k<<<(BB * 10 + 255) / 256, 256, 0, stream>>>(PO, dw, db, out);
}

// Round 10
// 805.601 us; speedup vs baseline: 2.3982x; 1.2303x over previous
//
#include <hip/hip_runtime.h>
#include <hip/hip_bf16.h>

#define HD 512      // d_model
#define NST 64      // d_state
#define NLAY 6
#define LSEQ 784
#define BB 64       // batch
#define CHK 7       // l-tiles (16 rows) per conv block; 49 = 7*7
#define NKA 848     // reversed+padded kernel array length (u16)
#define TOFF 798    // KA[t] = K[TOFF - t]; t in [15,798] real, else 0
#define LPADROWS 800  // Vb row capacity (16 rows slack for j over-read)
#define UTS 19      // UT row stride (dwords): 2-way banks max on reads+writes

typedef unsigned short u16;
typedef short s8v __attribute__((ext_vector_type(8)));   // 8 bf16 (4 VGPR)
typedef float f4v __attribute__((ext_vector_type(4)));   // MFMA acc
typedef u16  u4h __attribute__((ext_vector_type(4)));    // ushort4 (8B)

// fp32 -> bf16 bits, round-to-nearest-even
__device__ __forceinline__ unsigned f2b(float f)
{
    unsigned u = __builtin_bit_cast(unsigned, f);
    return (u + 0x7FFFu + ((u >> 16) & 1u)) >> 16;
}
__device__ __forceinline__ float b2f16(u16 v)
{
    unsigned u = ((unsigned)v) << 16;
    return __builtin_bit_cast(float, u);
}

// ---------------------------------------------------------------------------
// Per (layer,h,n): lambda = exp(dt*A), dtA, 2*Cd. Layout [i][h][n].
// ---------------------------------------------------------------------------
__global__ void precompute_k(const float* __restrict__ log_dt,
                             const float* __restrict__ log_A_real,
                             const float* __restrict__ A_imag,
                             const float* __restrict__ C_re,
                             const float* __restrict__ C_im,
                             float* __restrict__ lamr, float* __restrict__ lami,
                             float* __restrict__ dtr,  float* __restrict__ dti,
                             float* __restrict__ c2r,  float* __restrict__ c2i)
{
    int t = blockIdx.x * 256 + threadIdx.x;
    if (t >= NLAY * HD * NST) return;
    int ih = t >> 6;                       // i*HD + h
    float dt  = expf(log_dt[ih]);
    float are = -expf(log_A_real[t]);
    float aim = A_imag[t];
    float dr = are * dt, di = aim * dt;
    float er = expf(dr);
    float sn, cs; __sincosf(di, &sn, &cs);
    float lr = er * cs, li = er * sn;      // lambda
    float e1r = lr - 1.0f, e1i = li;
    float den = are * are + aim * aim;
    float qr = (e1r * are + e1i * aim) / den;
    float qi = (e1i * are - e1r * aim) / den;
    float crv = C_re[t], civ = C_im[t];
    lamr[t] = lr; lami[t] = li; dtr[t] = dr; dti[t] = di;
    c2r[t] = 2.0f * (crv * qr - civ * qi);
    c2i[t] = 2.0f * (crv * qi + civ * qr);
}

// ---------------------------------------------------------------------------
// Build KA[i][h][t] (bf16): reversed, zero-padded conv kernel.
// ---------------------------------------------------------------------------
__global__ void kq_k(const float* __restrict__ lamr, const float* __restrict__ lami,
                     const float* __restrict__ dtr,  const float* __restrict__ dti,
                     const float* __restrict__ c2r,  const float* __restrict__ c2i,
                     u16* __restrict__ KA)
{
    int t = blockIdx.x * 256 + threadIdx.x;   // < 6*512*49
    int dc = t % 49;
    int ih = t / 49;                          // i*HD + h
    int d0 = dc * 16;
    float acc[16];
#pragma unroll
    for (int k = 0; k < 16; k++) acc[k] = 0.f;
    int base = ih * 64;
    for (int n = 0; n < 64; n++) {
        float lr = lamr[base + n], li = lami[base + n];
        float dr = dtr[base + n],  di = dti[base + n];
        float cr = c2r[base + n],  ci = c2i[base + n];
        float e = __expf(dr * (float)d0);
        float sn, cs; __sincosf(di * (float)d0, &sn, &cs);
        float pr = e * cs, pi = e * sn;       // lam^d0
#pragma unroll
        for (int k = 0; k < 16; k++) {
            acc[k] = fmaf(cr, pr, fmaf(-ci, pi, acc[k]));
            float nr = pr * lr - pi * li;
            pi = fmaf(pr, li, pi * lr);
            pr = nr;
        }
    }
    u16* kap = KA + (size_t)ih * NKA;
#pragma unroll
    for (int k = 0; k < 16; k++)
        kap[TOFF - (d0 + k)] = (u16)f2b(acc[k]);
    if (dc == 0)  for (int z = TOFF + 1; z < NKA; z++) kap[z] = 0;
    if (dc == 48) for (int z = 0; z < TOFF - 783; z++) kap[z] = 0;
}

// ---------------------------------------------------------------------------
// Encoder into bf16 [l][h][b]: Vb = bf16(x[b,l]*ew[h]+eb[h])
// ---------------------------------------------------------------------------
__global__ void encoder_k(const float* __restrict__ x, const float* __restrict__ ew,
                          const float* __restrict__ eb, u16* __restrict__ Vb)
{
    size_t g = (size_t)blockIdx.x * 256 + threadIdx.x;
    int b = (int)(g & 63);
    int h = (int)((g >> 6) & 511);
    int l = (int)(g >> 15);
    Vb[g] = (u16)f2b(fmaf(x[b * LSEQ + l], ew[h], eb[h]));
}

// ---------------------------------------------------------------------------
// MFMA causal-Toeplitz conv + residual: V2 = conv(K_h, Vb) + (1+D_h)*Vb.
// Block = (h, chunk c of 7 l-tiles) x 4 waves (4 b-tiles of 16).
// B staged from bf16 Vb: ushort4 pair loads + 4 pack ORs (no f2b), UT
// stride 19 (max 2-way LDS banks on both stage-writes and frag-reads).
// A-frag from parity-duplicated KS (zeros => causality). One barrier per
// j-step; next tile's global loads issued before compute.
// ---------------------------------------------------------------------------
__global__ __launch_bounds__(256)
void conv_k(const u16* __restrict__ Vb, float* __restrict__ V2,
            const u16* __restrict__ KA, const float* __restrict__ Dvec)
{
    __shared__ u16 KS[2 * NKA];            // rev-K + odd-shift copy
    __shared__ unsigned UT[2][64 * UTS];   // [buf][b*UTS + jj], jj = j/2

    const int thr = threadIdx.x;
    const int h   = blockIdx.x & 511;
    const int c   = blockIdx.x >> 9;         // 0..6
    const int wid = thr >> 6;                // b-tile
    const int lane = thr & 63;
    const int n = lane & 15;
    const int q = lane >> 4;
    const int JTN = (112 * c + 111) / 32 + 1;

    // stage KS + odd-shifted copy
    const u16* kap = KA + (size_t)h * NKA;
    for (int idx = thr; idx < NKA; idx += 256) {
        u16 v = kap[idx];
        KS[idx] = v;
        if (idx) KS[NKA + idx - 1] = v;
    }
    if (thr == 0) KS[2 * NKA - 1] = 0;

    // staging mapping: thread = (jj = j-pair 0..15, bq = b-quad 0..15)
    const int jj = thr >> 4;
    const int bq = thr & 15;
    {   // stage tile jt=0
        const u16* p = &Vb[((size_t)(2 * jj) * HD + h) * BB + 4 * bq];
        u4h r0 = *(const u4h*)p;
        u4h r1 = *(const u4h*)(p + (size_t)HD * BB);
        unsigned* up = &UT[0][0];
#pragma unroll
        for (int i = 0; i < 4; i++)
            up[(4 * bq + i) * UTS + jj] = (unsigned)r0[i] | ((unsigned)r1[i] << 16);
    }
    __syncthreads();

    f4v acc[CHK];
#pragma unroll
    for (int i = 0; i < CHK; i++) acc[i] = (f4v){0.f, 0.f, 0.f, 0.f};

    const float dcoef = 1.0f + Dvec[h];

    for (int jt = 0; jt < JTN; ++jt) {
        const int buf = jt & 1;
        const int j0 = jt * 32;
        // issue next tile's global loads (consumed after compute)
        u4h r0, r1;
        const bool more = (jt + 1) < JTN;
        if (more) {
            int j = (jt + 1) * 32 + 2 * jj;  // rows >783: slack rows, zero-A kills
            const u16* p = &Vb[((size_t)j * HD + h) * BB + 4 * bq];
            r0 = *(const u4h*)p;
            r1 = *(const u4h*)(p + (size_t)HD * BB);
        }
        // B fragment (same for all l-tiles this step)
        union { unsigned u[4]; s8v v; } bu;
        {
            const unsigned* bp = &UT[buf][(wid * 16 + n) * UTS + q * 4];
            bu.u[0] = bp[0]; bu.u[1] = bp[1]; bu.u[2] = bp[2]; bu.u[3] = bp[3];
        }
#pragma unroll
        for (int lt = 0; lt < CHK; ++lt) {
            const int Lt = c * CHK + lt;
            if (16 * Lt + 15 < j0) continue;            // inactive (uniform)
            const int l0 = Lt * 16;
            int tb = (TOFF - l0 + j0) + 8 * q - n;      // lane's first KA index
            int par = tb & 1;
            int byteoff = 2 * tb + (par ? (2 * NKA - 2) : 0);
            const unsigned* ap = (const unsigned*)((const char*)KS + byteoff);
            union { unsigned u[4]; s8v v; } au;
            au.u[0] = ap[0]; au.u[1] = ap[1]; au.u[2] = ap[2]; au.u[3] = ap[3];
            acc[lt] = __builtin_amdgcn_mfma_f32_16x16x32_bf16(au.v, bu.v, acc[lt], 0, 0, 0);
        }
        if (more) {
            unsigned* up = &UT[buf ^ 1][0];
#pragma unroll
            for (int i = 0; i < 4; i++)
                up[(4 * bq + i) * UTS + jj] = (unsigned)r0[i] | ((unsigned)r1[i] << 16);
        }
        __syncthreads();
    }

    // epilogue: V2 = y + (1+D)*u  (pre-LN residual), fp32 out
#pragma unroll
    for (int lt = 0; lt < CHK; ++lt) {
        const int l0 = (c * CHK + lt) * 16;
#pragma unroll
        for (int r = 0; r < 4; ++r) {
            int l = l0 + q * 4 + r;
            size_t a = ((size_t)l * HD + h) * BB + wid * 16 + n;
            V2[a] = fmaf(dcoef, b2f16(Vb[a]), acc[lt][r]);
        }
    }
}

// ---------------------------------------------------------------------------
// LayerNorm over h in [l][h][b] layout; fp32 or bf16 src, bf16 dst.
// Block = one l, 512 threads: thread (b, hg) holds 64 h-values.
// ---------------------------------------------------------------------------
template <int SRCBF>
__global__ __launch_bounds__(512)
void lnT_k(const float* __restrict__ srcF, const u16* __restrict__ srcB,
           u16* __restrict__ dst,
           const float* __restrict__ gp, const float* __restrict__ bp)
{
    __shared__ float red[8][64], redq[8][64], mus[64], rss[64];
    __shared__ float gs[512], bs[512];
    const int thr = threadIdx.x;
    const int b = thr & 63;
    const int hg = thr >> 6;
    const size_t l = blockIdx.x;
    gs[thr] = gp[thr]; bs[thr] = bp[thr];

    float v[64];
    float s = 0.f, sq = 0.f;
    if (SRCBF) {
        const u16* sp = &srcB[(l * HD + hg * 64) * BB + b];
#pragma unroll
        for (int k = 0; k < 64; k++) {
            float x = b2f16(sp[(size_t)k * BB]);
            v[k] = x; s += x; sq = fmaf(x, x, sq);
        }
    } else {
        const float* sp = &srcF[(l * HD + hg * 64) * BB + b];
#pragma unroll
        for (int k = 0; k < 64; k++) {
            float x = sp[(size_t)k * BB];
            v[k] = x; s += x; sq = fmaf(x, x, sq);
        }
    }
    red[hg][b] = s; redq[hg][b] = sq;
    __syncthreads();
    if (thr < 64) {
        float ts = 0.f, tq = 0.f;
#pragma unroll
        for (int k = 0; k < 8; k++) { ts += red[k][thr]; tq += redq[k][thr]; }
        float mu = ts * (1.0f / HD);
        mus[thr] = mu;
        rss[thr] = rsqrtf(tq * (1.0f / HD) - mu * mu + 1e-5f);
    }
    __syncthreads();
    float mu = mus[b], rs = rss[b];
    u16* dp = &dst[(l * HD + hg * 64) * BB + b];
#pragma unroll
    for (int k = 0; k < 64; k++) {
        int hh = hg * 64 + k;
        dp[(size_t)k * BB] = (u16)f2b(fmaf((v[k] - mu) * rs, gs[hh], bs[hh]));
    }
}

// ---------------------------------------------------------------------------
// Mean-pool over l from bf16 Vb: PO[h*64+b] = mean_l Vb[l][h][b].
// ---------------------------------------------------------------------------
__global__ void pool_k(const u16* __restrict__ Vb, float* __restrict__ PO)
{
    __shared__ float red[4][64];
    int h = blockIdx.x;
    int b = threadIdx.x & 63;
    int lg = threadIdx.x >> 6;               // 0..3
    const u16* p = &Vb[(size_t)h * BB + b];
    float s = 0.f;
    for (int l = lg; l < LSEQ; l += 4) s += b2f16(p[(size_t)l * HD * BB]);
    red[lg][b] = s;
    __syncthreads();
    if (threadIdx.x < 64) {
        float t = red[0][b] + red[1][b] + red[2][b] + red[3][b];
        PO[h * BB + b] = t * (1.0f / LSEQ);
    }
}

// ---------------------------------------------------------------------------
// Decoder: out[b,c] = PO[:,b] . dec_w[:,c] + dec_b[c]
// ---------------------------------------------------------------------------
__global__ void dec_k(const float* __restrict__ PO, const float* __restrict__ w,
                      const float* __restrict__ bias, float* __restrict__ out)
{
    int t = blockIdx.x * 256 + threadIdx.x;
    if (t >= BB * 10) return;
    int cc = t % 10, b = t / 10;
    float acc = bias[cc];
    for (int hh = 0; hh < HD; hh++)
        acc = fmaf(PO[hh * BB + b], w[hh * 10 + cc], acc);
    out[t] = acc;
}

// ---------------------------------------------------------------------------
extern "C" void kernel_launch(void* const* d_in, const int* in_sizes, int n_in,
                              void* d_out, int out_size, void* d_ws, size_t ws_size,
                              hipStream_t stream)
{
    const float* x   = (const float*)d_in[0];
    const float* ew  = (const float*)d_in[1];
    const float* eb  = (const float*)d_in[2];
    const float* ldt = (const float*)d_in[3];
    const float* lar = (const float*)d_in[4];
    const float* aim = (const float*)d_in[5];
    const float* cre = (const float*)d_in[6];
    const float* cim = (const float*)d_in[7];
    const float* Dp  = (const float*)d_in[8];
    const float* lng = (const float*)d_in[9];
    const float* lnb = (const float*)d_in[10];
    const float* fng = (const float*)d_in[11];
    const float* fnb = (const float*)d_in[12];
    const float* dw  = (const float*)d_in[13];
    const float* db  = (const float*)d_in[14];
    float* out = (float*)d_out;

    float* ws = (float*)d_ws;
    const size_t SZ  = (size_t)BB * LSEQ * HD;       // 25,690,112 floats
    const size_t SZB = (size_t)BB * LPADROWS * HD;   // 26,214,400 u16 slots
    const size_t PP  = (size_t)NLAY * HD * NST;      // 196,608
    u16*   Vb  = (u16*)ws;                  // bf16 residual stream [l][h][b]
    float* V2  = ws + SZB / 2;              // pre-LN buffer, fp32
    float* PAR = V2 + SZ;
    float* lamr = PAR,        * lami = PAR + PP;
    float* dtr  = PAR + 2*PP, * dti  = PAR + 3*PP;
    float* c2r  = PAR + 4*PP, * c2i  = PAR + 5*PP;
    u16* KA = (u16*)(PAR + 6 * PP);                  // 6*512*848 u16
    float* PO = PAR + 6 * PP + (NLAY * HD * NKA) / 2;
    // total ~166 MB

    precompute_k<<<(NLAY * HD * NST + 255) / 256, 256, 0, stream>>>(
        ldt, lar, aim, cre, cim, lamr, lami, dtr, dti, c2r, c2i);
    kq_k<<<(NLAY * HD * 49) / 256, 256, 0, stream>>>(
        lamr, lami, dtr, dti, c2r, c2i, KA);
    encoder_k<<<(int)(SZ / 256), 256, 0, stream>>>(x, ew, eb, Vb);

    for (int i = 0; i < NLAY; i++) {
        conv_k<<<512 * CHK, 256, 0, stream>>>(
            Vb, V2, KA + (size_t)i * HD * NKA, Dp + i * HD);
        lnT_k<0><<<LSEQ, 512, 0, stream>>>(V2, nullptr, Vb,
                                           lng + i * HD, lnb + i * HD);
    }
    lnT_k<1><<<LSEQ, 512, 0, stream>>>(nullptr, Vb, Vb, fng, fnb);  // in-place
    pool_k<<<HD, 256, 0, stream>>>(Vb, PO);
    dec_k<<<(BB * 10 + 255) / 256, 256, 0, stream>>>(PO, dw, db, out);
}

// Round 11
// 765.252 us; speedup vs baseline: 2.5246x; 1.0527x over previous
//
#include <hip/hip_runtime.h>
#include <hip/hip_bf16.h>

#define HD 512      // d_model
#define NST 64      // d_state
#define NLAY 6
#define LSEQ 784
#define BB 64       // batch
#define CHK 7       // l-tiles (16 rows) per conv block; 49 = 7*7
#define NKA 848     // reversed+padded kernel array length (u16)
#define TOFF 798    // KA[t] = K[TOFF - t]; t in [15,798] real, else 0
#define LPADROWS 800  // Vb row capacity (16 rows slack for j over-read)
#define UTS 19      // UT row stride (dwords): <=2-way banks (measured free)
#define KSTR 850    // u16 stride between shifted K copies (dword 425 == 9 mod 32)

typedef unsigned short u16;
typedef short s8v __attribute__((ext_vector_type(8)));   // 8 bf16 (4 VGPR)
typedef float f4v __attribute__((ext_vector_type(4)));   // MFMA acc
typedef u16  u4h __attribute__((ext_vector_type(4)));    // ushort4 (8B)

// fp32 -> bf16 bits, round-to-nearest-even
__device__ __forceinline__ unsigned f2b(float f)
{
    unsigned u = __builtin_bit_cast(unsigned, f);
    return (u + 0x7FFFu + ((u >> 16) & 1u)) >> 16;
}
__device__ __forceinline__ float b2f16(u16 v)
{
    unsigned u = ((unsigned)v) << 16;
    return __builtin_bit_cast(float, u);
}

// ---------------------------------------------------------------------------
// Per (layer,h,n): lambda = exp(dt*A), dtA, 2*Cd. Layout [i][h][n].
// ---------------------------------------------------------------------------
__global__ void precompute_k(const float* __restrict__ log_dt,
                             const float* __restrict__ log_A_real,
                             const float* __restrict__ A_imag,
                             const float* __restrict__ C_re,
                             const float* __restrict__ C_im,
                             float* __restrict__ lamr, float* __restrict__ lami,
                             float* __restrict__ dtr,  float* __restrict__ dti,
                             float* __restrict__ c2r,  float* __restrict__ c2i)
{
    int t = blockIdx.x * 256 + threadIdx.x;
    if (t >= NLAY * HD * NST) return;
    int ih = t >> 6;                       // i*HD + h
    float dt  = expf(log_dt[ih]);
    float are = -expf(log_A_real[t]);
    float aim = A_imag[t];
    float dr = are * dt, di = aim * dt;
    float er = expf(dr);
    float sn, cs; __sincosf(di, &sn, &cs);
    float lr = er * cs, li = er * sn;      // lambda
    float e1r = lr - 1.0f, e1i = li;
    float den = are * are + aim * aim;
    float qr = (e1r * are + e1i * aim) / den;
    float qi = (e1i * are - e1r * aim) / den;
    float crv = C_re[t], civ = C_im[t];
    lamr[t] = lr; lami[t] = li; dtr[t] = dr; dti[t] = di;
    c2r[t] = 2.0f * (crv * qr - civ * qi);
    c2i[t] = 2.0f * (crv * qi + civ * qr);
}

// ---------------------------------------------------------------------------
// Build KA[i][h][t] (bf16): reversed, zero-padded conv kernel.
// ---------------------------------------------------------------------------
__global__ void kq_k(const float* __restrict__ lamr, const float* __restrict__ lami,
                     const float* __restrict__ dtr,  const float* __restrict__ dti,
                     const float* __restrict__ c2r,  const float* __restrict__ c2i,
                     u16* __restrict__ KA)
{
    int t = blockIdx.x * 256 + threadIdx.x;   // < 6*512*49
    int dc = t % 49;
    int ih = t / 49;                          // i*HD + h
    int d0 = dc * 16;
    float acc[16];
#pragma unroll
    for (int k = 0; k < 16; k++) acc[k] = 0.f;
    int base = ih * 64;
    for (int n = 0; n < 64; n++) {
        float lr = lamr[base + n], li = lami[base + n];
        float dr = dtr[base + n],  di = dti[base + n];
        float cr = c2r[base + n],  ci = c2i[base + n];
        float e = __expf(dr * (float)d0);
        float sn, cs; __sincosf(di * (float)d0, &sn, &cs);
        float pr = e * cs, pi = e * sn;       // lam^d0
#pragma unroll
        for (int k = 0; k < 16; k++) {
            acc[k] = fmaf(cr, pr, fmaf(-ci, pi, acc[k]));
            float nr = pr * lr - pi * li;
            pi = fmaf(pr, li, pi * lr);
            pr = nr;
        }
    }
    u16* kap = KA + (size_t)ih * NKA;
#pragma unroll
    for (int k = 0; k < 16; k++)
        kap[TOFF - (d0 + k)] = (u16)f2b(acc[k]);
    if (dc == 0)  for (int z = TOFF + 1; z < NKA; z++) kap[z] = 0;
    if (dc == 48) for (int z = 0; z < TOFF - 783; z++) kap[z] = 0;
}

// ---------------------------------------------------------------------------
// Encoder into bf16 [l][h][b]: Vb = bf16(x[b,l]*ew[h]+eb[h])
// ---------------------------------------------------------------------------
__global__ void encoder_k(const float* __restrict__ x, const float* __restrict__ ew,
                          const float* __restrict__ eb, u16* __restrict__ Vb)
{
    size_t g = (size_t)blockIdx.x * 256 + threadIdx.x;
    int b = (int)(g & 63);
    int h = (int)((g >> 6) & 511);
    int l = (int)(g >> 15);
    Vb[g] = (u16)f2b(fmaf(x[b * LSEQ + l], ew[h], eb[h]));
}

// ---------------------------------------------------------------------------
// MFMA causal-Toeplitz conv + residual: V2 = bf16(conv(K_h,Vb) + (1+D_h)*Vb).
// Block = (h, chunk c of 7 l-tiles) x 4 waves (4 b-tiles of 16).
// A-frags from 8 lane-shifted K copies KR[850*s + i + s] = K_rev[i], s=n&7:
// every lane's dword read is aligned and bank = 9s+4q-4(n>>3)+r -> <=2-way
// (free); lanes n,n+8 broadcast. Per-lt addresses are immediates off one
// per-jt base pointer (no per-lt VALU address chain).
// B from bf16 Vb staged in double-buffered UT (stride 19, <=2-way).
// One barrier per j-step; next tile's global loads issued before compute.
// ---------------------------------------------------------------------------
__global__ __launch_bounds__(256)
void conv_k(const u16* __restrict__ Vb, u16* __restrict__ V2,
            const u16* __restrict__ KA, const float* __restrict__ Dvec)
{
    __shared__ u16 KR[KSTR * 8 + 8];         // 8 shifted copies (~13.6 KB)
    __shared__ unsigned UT[2][64 * UTS];     // [buf][b*UTS + jj], jj = j/2

    const int thr = threadIdx.x;
    const int h   = blockIdx.x & 511;
    const int c   = blockIdx.x >> 9;         // 0..6
    const int wid = thr >> 6;                // b-tile
    const int lane = thr & 63;
    const int n = lane & 15;
    const int q = lane >> 4;
    const int JTN = (112 * c + 111) / 32 + 1;

    // stage 8 shifted K copies: KR[KSTR*s + i + s] = kap[i]
    const u16* kap = KA + (size_t)h * NKA;
    {
        int s = thr & 7, ch = thr >> 3;      // 32 chunks x 27 (covers 848)
        int i0 = ch * 27;
        int i1 = (i0 + 27 < NKA) ? (i0 + 27) : NKA;
        u16* kr = KR + KSTR * s + s;
        for (int i = i0; i < i1; i++) kr[i] = kap[i];
    }

    // staging mapping: thread = (jj = j-pair 0..15, bq = b-quad 0..15)
    const int jj = thr >> 4;
    const int bq = thr & 15;
    {   // stage tile jt=0
        const u16* p = &Vb[((size_t)(2 * jj) * HD + h) * BB + 4 * bq];
        u4h r0 = *(const u4h*)p;
        u4h r1 = *(const u4h*)(p + (size_t)HD * BB);
        unsigned* up = &UT[0][0];
#pragma unroll
        for (int i = 0; i < 4; i++)
            up[(4 * bq + i) * UTS + jj] = (unsigned)r0[i] | ((unsigned)r1[i] << 16);
    }
    __syncthreads();

    f4v acc[CHK];
#pragma unroll
    for (int i = 0; i < CHK; i++) acc[i] = (f4v){0.f, 0.f, 0.f, 0.f};

    const float dcoef = 1.0f + Dvec[h];

    // per-lane A base (lt=6, j0=0, r=0); per jt just add j0 (scalar)
    const u16* krb = KR + KSTR * (n & 7) + ((n & 7) - n)
                     + (TOFF - 112 * c - 96) + 8 * q;
    // B-frag base pointers (per buffer)
    const unsigned* bb0 = &UT[0][(wid * 16 + n) * UTS + 4 * q];
    const unsigned* bb1 = &UT[1][(wid * 16 + n) * UTS + 4 * q];

    for (int jt = 0; jt < JTN; ++jt) {
        const int j0 = jt * 32;
        // issue next tile's global loads (consumed after compute)
        u4h r0, r1;
        const bool more = (jt + 1) < JTN;
        if (more) {
            int j = (jt + 1) * 32 + 2 * jj;  // rows >783: slack rows, zero-A kills
            const u16* p = &Vb[((size_t)j * HD + h) * BB + 4 * bq];
            r0 = *(const u4h*)p;
            r1 = *(const u4h*)(p + (size_t)HD * BB);
        }
        // B fragment (same for all l-tiles this step)
        const unsigned* bb = (jt & 1) ? bb1 : bb0;
        union { unsigned u[4]; s8v v; } bu;
        bu.u[0] = bb[0]; bu.u[1] = bb[1]; bu.u[2] = bb[2]; bu.u[3] = bb[3];

        const u16* ap0 = krb + j0;
#pragma unroll
        for (int lt = 0; lt < CHK; ++lt) {
            if (16 * (c * CHK + lt) + 15 < j0) continue;   // future tile (uniform)
            const unsigned* ap = (const unsigned*)(ap0 + 16 * (6 - lt));
            union { unsigned u[4]; s8v v; } au;
            au.u[0] = ap[0]; au.u[1] = ap[1]; au.u[2] = ap[2]; au.u[3] = ap[3];
            acc[lt] = __builtin_amdgcn_mfma_f32_16x16x32_bf16(au.v, bu.v, acc[lt], 0, 0, 0);
        }
        if (more) {
            unsigned* up = &UT[(jt & 1) ^ 1][0];
#pragma unroll
            for (int i = 0; i < 4; i++)
                up[(4 * bq + i) * UTS + jj] = (unsigned)r0[i] | ((unsigned)r1[i] << 16);
        }
        __syncthreads();
    }

    // epilogue: V2 = bf16(y + (1+D)*u)  (pre-LN residual)
#pragma unroll
    for (int lt = 0; lt < CHK; ++lt) {
        const int l0 = (c * CHK + lt) * 16;
#pragma unroll
        for (int r = 0; r < 4; ++r) {
            int l = l0 + q * 4 + r;
            size_t a = ((size_t)l * HD + h) * BB + wid * 16 + n;
            V2[a] = (u16)f2b(fmaf(dcoef, b2f16(Vb[a]), acc[lt][r]));
        }
    }
}

// ---------------------------------------------------------------------------
// LayerNorm over h in [l][h][b] layout; bf16 src, bf16 dst (fp32 math).
// Block = one l, 512 threads: thread (b, hg) holds 64 h-values.
// ---------------------------------------------------------------------------
__global__ __launch_bounds__(512)
void lnT_k(const u16* __restrict__ src, u16* __restrict__ dst,
           const float* __restrict__ gp, const float* __restrict__ bp)
{
    __shared__ float red[8][64], redq[8][64], mus[64], rss[64];
    __shared__ float gs[512], bs[512];
    const int thr = threadIdx.x;
    const int b = thr & 63;
    const int hg = thr >> 6;
    const size_t l = blockIdx.x;
    gs[thr] = gp[thr]; bs[thr] = bp[thr];

    const u16* sp = &src[(l * HD + hg * 64) * BB + b];
    float v[64];
    float s = 0.f, sq = 0.f;
#pragma unroll
    for (int k = 0; k < 64; k++) {
        float x = b2f16(sp[(size_t)k * BB]);
        v[k] = x; s += x; sq = fmaf(x, x, sq);
    }
    red[hg][b] = s; redq[hg][b] = sq;
    __syncthreads();
    if (thr < 64) {
        float ts = 0.f, tq = 0.f;
#pragma unroll
        for (int k = 0; k < 8; k++) { ts += red[k][thr]; tq += redq[k][thr]; }
        float mu = ts * (1.0f / HD);
        mus[thr] = mu;
        rss[thr] = rsqrtf(tq * (1.0f / HD) - mu * mu + 1e-5f);
    }
    __syncthreads();
    float mu = mus[b], rs = rss[b];
    u16* dp = &dst[(l * HD + hg * 64) * BB + b];
#pragma unroll
    for (int k = 0; k < 64; k++) {
        int hh = hg * 64 + k;
        dp[(size_t)k * BB] = (u16)f2b(fmaf((v[k] - mu) * rs, gs[hh], bs[hh]));
    }
}

// ---------------------------------------------------------------------------
// Mean-pool over l from bf16 Vb: PO[h*64+b] = mean_l Vb[l][h][b].
// ---------------------------------------------------------------------------
__global__ void pool_k(const u16* __restrict__ Vb, float* __restrict__ PO)
{
    __shared__ float red[4][64];
    int h = blockIdx.x;
    int b = threadIdx.x & 63;
    int lg = threadIdx.x >> 6;               // 0..3
    const u16* p = &Vb[(size_t)h * BB + b];
    float s = 0.f;
    for (int l = lg; l < LSEQ; l += 4) s += b2f16(p[(size_t)l * HD * BB]);
    red[lg][b] = s;
    __syncthreads();
    if (threadIdx.x < 64) {
        float t = red[0][b] + red[1][b] + red[2][b] + red[3][b];
        PO[h * BB + b] = t * (1.0f / LSEQ);
    }
}

// ---------------------------------------------------------------------------
// Decoder: out[b,c] = PO[:,b] . dec_w[:,c] + dec_b[c]
// ---------------------------------------------------------------------------
__global__ void dec_k(const float* __restrict__ PO, const float* __restrict__ w,
                      const float* __restrict__ bias, float* __restrict__ out)
{
    int t = blockIdx.x * 256 + threadIdx.x;
    if (t >= BB * 10) return;
    int cc = t % 10, b = t / 10;
    float acc = bias[cc];
    for (int hh = 0; hh < HD; hh++)
        acc = fmaf(PO[hh * BB + b], w[hh * 10 + cc], acc);
    out[t] = acc;
}

// ---------------------------------------------------------------------------
extern "C" void kernel_launch(void* const* d_in, const int* in_sizes, int n_in,
                              void* d_out, int out_size, void* d_ws, size_t ws_size,
                              hipStream_t stream)
{
    const float* x   = (const float*)d_in[0];
    const float* ew  = (const float*)d_in[1];
    const float* eb  = (const float*)d_in[2];
    const float* ldt = (const float*)d_in[3];
    const float* lar = (const float*)d_in[4];
    const float* aim = (const float*)d_in[5];
    const float* cre = (const float*)d_in[6];
    const float* cim = (const float*)d_in[7];
    const float* Dp  = (const float*)d_in[8];
    const float* lng = (const float*)d_in[9];
    const float* lnb = (const float*)d_in[10];
    const float* fng = (const float*)d_in[11];
    const float* fnb = (const float*)d_in[12];
    const float* dw  = (const float*)d_in[13];
    const float* db  = (const float*)d_in[14];
    float* out = (float*)d_out;

    const size_t SZ  = (size_t)BB * LSEQ * HD;       // 25,690,112 elems
    const size_t SZB = (size_t)BB * LPADROWS * HD;   // 26,214,400 u16 slots
    const size_t PP  = (size_t)NLAY * HD * NST;      // 196,608
    u16*   Vb  = (u16*)d_ws;                // bf16 residual stream [l][h][b]
    u16*   V2  = Vb + SZB;                  // bf16 pre-LN buffer
    float* PAR = (float*)(V2 + SZ);
    float* lamr = PAR,        * lami = PAR + PP;
    float* dtr  = PAR + 2*PP, * dti  = PAR + 3*PP;
    float* c2r  = PAR + 4*PP, * c2i  = PAR + 5*PP;
    u16* KA = (u16*)(PAR + 6 * PP);                  // 6*512*848 u16
    float* PO = PAR + 6 * PP + (NLAY * HD * NKA) / 2;
    // total ~116 MB

    precompute_k<<<(NLAY * HD * NST + 255) / 256, 256, 0, stream>>>(
        ldt, lar, aim, cre, cim, lamr, lami, dtr, dti, c2r, c2i);
    kq_k<<<(NLAY * HD * 49) / 256, 256, 0, stream>>>(
        lamr, lami, dtr, dti, c2r, c2i, KA);
    encoder_k<<<(int)(SZ / 256), 256, 0, stream>>>(x, ew, eb, Vb);

    for (int i = 0; i < NLAY; i++) {
        conv_k<<<512 * CHK, 256, 0, stream>>>(
            Vb, V2, KA + (size_t)i * HD * NKA, Dp + i * HD);
        lnT_k<<<LSEQ, 512, 0, stream>>>(V2, Vb, lng + i * HD, lnb + i * HD);
    }
    lnT_k<<<LSEQ, 512, 0, stream>>>(Vb, Vb, fng, fnb);  // final LN in place
    pool_k<<<HD, 256, 0, stream>>>(Vb, PO);
    dec_k<<<(BB * 10 + 255) / 256, 256, 0, stream>>>(PO, dw, db, out);
}